// Round 1
// baseline (2304.635 us; speedup 1.0000x reference)
//
#include <hip/hip_runtime.h>
#include <math.h>

#define BB    32
#define CCH   64
#define DIMN  1024
#define NCLS  10

// ---------------------------------------------------------------------------
// 1) transpose: image (B,C,DIM) -> X (B,DIM,C), LDS-tiled, coalesced both ways
// ---------------------------------------------------------------------------
__global__ __launch_bounds__(256) void k_transpose(const float* __restrict__ img,
                                                   float* __restrict__ X) {
  __shared__ float tile[64][65];
  const int b  = blockIdx.y;
  const int n0 = blockIdx.x * 64;
  const int tx = threadIdx.x & 63;
  const int ty = threadIdx.x >> 6;
  const float* src = img + (size_t)b * CCH * DIMN;
  #pragma unroll
  for (int c = ty; c < 64; c += 4)
    tile[c][tx] = src[(size_t)c * DIMN + n0 + tx];
  __syncthreads();
  float* dst = X + (size_t)b * DIMN * CCH;
  #pragma unroll
  for (int nn = ty; nn < 64; nn += 4)
    dst[(size_t)(n0 + nn) * CCH + tx] = tile[tx][nn];
}

// ---------------------------------------------------------------------------
// 2) QKV projection: Q/K/V[n,c] = sum_j X[n,j] * W{q,k,v}[j,c]
//    block = 256 threads = 16 tokens; X rows broadcast from LDS, weights via L1
// ---------------------------------------------------------------------------
__global__ __launch_bounds__(256) void k_qkv(
    const float* __restrict__ X,
    const float* __restrict__ WQ, const float* __restrict__ WK,
    const float* __restrict__ WV,
    float* __restrict__ Q, float* __restrict__ K, float* __restrict__ V) {
  __shared__ float xs[16][64];
  const int c  = threadIdx.x & 63;
  const int tg = threadIdx.x >> 6;   // 0..3
  const size_t t0 = (size_t)blockIdx.x * 16;
  #pragma unroll
  for (int r = tg; r < 16; r += 4)
    xs[r][c] = X[(t0 + r) * 64 + c];
  __syncthreads();
  float qa[4] = {0.f,0.f,0.f,0.f};
  float ka[4] = {0.f,0.f,0.f,0.f};
  float va[4] = {0.f,0.f,0.f,0.f};
  for (int j = 0; j < 64; ++j) {
    const float wq = WQ[j * 64 + c];
    const float wk = WK[j * 64 + c];
    const float wv = WV[j * 64 + c];
    #pragma unroll
    for (int r = 0; r < 4; ++r) {
      const float x = xs[tg * 4 + r][j];
      qa[r] = fmaf(x, wq, qa[r]);
      ka[r] = fmaf(x, wk, ka[r]);
      va[r] = fmaf(x, wv, va[r]);
    }
  }
  #pragma unroll
  for (int r = 0; r < 4; ++r) {
    const size_t idx = (t0 + tg * 4 + r) * 64 + c;
    Q[idx] = qa[r]; K[idx] = ka[r]; V[idx] = va[r];
  }
}

// ---------------------------------------------------------------------------
// 3) flash attention (fp32, online softmax), in-place residual:
//    X[rows] = (softmax(Q Kt / 32) @ V) + X[rows]
//    block = (batch, 64-row Q tile); 4x4 register blocking; stride-68 LDS pad
//    (all hot access patterns are <=2-way bank aliased = free on CDNA4)
// ---------------------------------------------------------------------------
__global__ __launch_bounds__(256) void k_attn(
    const float* __restrict__ Qg, const float* __restrict__ Kg,
    const float* __restrict__ Vg, float* __restrict__ X) {
  __shared__ __align__(16) float Qs[64][68];
  __shared__ __align__(16) float Ks[64][68];
  __shared__ __align__(16) float Vs[64][68];
  __shared__ __align__(16) float Ss[64][68];
  __shared__ float red4[64][4];
  __shared__ float mrow[64], lrow[64], arow[64];

  const int tid = threadIdx.x;
  const int it  = tid & 15;    // i-block (query rows it+16r)
  const int jt  = tid >> 4;    // j-block (key cols 4jt+c / channel cols 4jt+c)
  const int b   = blockIdx.y;
  const int i0  = blockIdx.x * 64;
  const size_t base = (size_t)b * (DIMN * 64);
  const float scale = 0.03125f;  // DIM^-0.5 = 1/32

  // stage Q tile (rows i0..i0+63 are one contiguous 16 KB block)
  {
    const float* src = Qg + base + (size_t)i0 * 64;
    #pragma unroll
    for (int p = 0; p < 4; ++p) {
      const int l = p * 256 + tid;
      *(float4*)&Qs[l >> 4][(l & 15) * 4] = *(const float4*)(src + 4 * l);
    }
  }
  if (tid < 64) { mrow[tid] = -INFINITY; lrow[tid] = 0.f; }

  float O[4][4];
  #pragma unroll
  for (int r = 0; r < 4; ++r)
    #pragma unroll
    for (int c = 0; c < 4; ++c) O[r][c] = 0.f;

  for (int kt = 0; kt < 16; ++kt) {
    __syncthreads();  // protect Ks/Vs/Ss reuse from previous iteration
    {
      const float* srcK = Kg + base + (size_t)kt * 4096;
      const float* srcV = Vg + base + (size_t)kt * 4096;
      #pragma unroll
      for (int p = 0; p < 4; ++p) {
        const int l = p * 256 + tid;
        *(float4*)&Ks[l >> 4][(l & 15) * 4] = *(const float4*)(srcK + 4 * l);
        *(float4*)&Vs[l >> 4][(l & 15) * 4] = *(const float4*)(srcV + 4 * l);
      }
    }
    __syncthreads();

    // S[i][j] = Q[i,:] . K[j,:]   (i = it+16r, j = 4jt+c)
    float s[4][4];
    #pragma unroll
    for (int r = 0; r < 4; ++r)
      #pragma unroll
      for (int c = 0; c < 4; ++c) s[r][c] = 0.f;
    for (int d = 0; d < 64; d += 4) {
      float4 q4[4], k4[4];
      #pragma unroll
      for (int r = 0; r < 4; ++r) q4[r] = *(const float4*)&Qs[it + 16 * r][d];
      #pragma unroll
      for (int c = 0; c < 4; ++c) k4[c] = *(const float4*)&Ks[4 * jt + c][d];
      #pragma unroll
      for (int r = 0; r < 4; ++r)
        #pragma unroll
        for (int c = 0; c < 4; ++c)
          s[r][c] += q4[r].x * k4[c].x + q4[r].y * k4[c].y +
                     q4[r].z * k4[c].z + q4[r].w * k4[c].w;
    }
    #pragma unroll
    for (int r = 0; r < 4; ++r) {
      float4 v;
      v.x = s[r][0] * scale; v.y = s[r][1] * scale;
      v.z = s[r][2] * scale; v.w = s[r][3] * scale;
      *(float4*)&Ss[it + 16 * r][4 * jt] = v;
    }
    __syncthreads();

    // online softmax: 4 threads per row, interleaved columns (bank-friendly)
    const int row = tid >> 2, sub = tid & 3;
    float pm = -INFINITY;
    #pragma unroll
    for (int j = 0; j < 16; ++j) pm = fmaxf(pm, Ss[row][sub + 4 * j]);
    red4[row][sub] = pm;
    __syncthreads();
    if (sub == 0) {
      float mn = fmaxf(fmaxf(red4[row][0], red4[row][1]),
                       fmaxf(red4[row][2], red4[row][3]));
      mn = fmaxf(mn, mrow[row]);
      arow[row] = __expf(mrow[row] - mn);  // first iter: exp(-inf)=0
      mrow[row] = mn;
    }
    __syncthreads();
    const float mn = mrow[row];
    float ps = 0.f;
    #pragma unroll
    for (int j = 0; j < 16; ++j) {
      const float p = __expf(Ss[row][sub + 4 * j] - mn);
      Ss[row][sub + 4 * j] = p;
      ps += p;
    }
    red4[row][sub] = ps;
    __syncthreads();
    if (sub == 0)
      lrow[row] = lrow[row] * arow[row] +
                  (red4[row][0] + red4[row][1] + red4[row][2] + red4[row][3]);

    // O = O*alpha + P @ V   (channels 4jt..4jt+3)
    #pragma unroll
    for (int r = 0; r < 4; ++r) {
      const float a = arow[it + 16 * r];
      #pragma unroll
      for (int c = 0; c < 4; ++c) O[r][c] *= a;
    }
    for (int j = 0; j < 64; j += 4) {
      const float4 va = *(const float4*)&Vs[j + 0][4 * jt];
      const float4 vb = *(const float4*)&Vs[j + 1][4 * jt];
      const float4 vc = *(const float4*)&Vs[j + 2][4 * jt];
      const float4 vd = *(const float4*)&Vs[j + 3][4 * jt];
      #pragma unroll
      for (int r = 0; r < 4; ++r) {
        const float4 p = *(const float4*)&Ss[it + 16 * r][j];
        O[r][0] += p.x * va.x + p.y * vb.x + p.z * vc.x + p.w * vd.x;
        O[r][1] += p.x * va.y + p.y * vb.y + p.z * vc.y + p.w * vd.y;
        O[r][2] += p.x * va.z + p.y * vb.z + p.z * vc.z + p.w * vd.z;
        O[r][3] += p.x * va.w + p.y * vb.w + p.z * vc.w + p.w * vd.w;
      }
    }
  }
  __syncthreads();  // lrow final values

  // X[rows] += O / l   (tau = 1). Block owns these rows exclusively -> in-place.
  #pragma unroll
  for (int r = 0; r < 4; ++r) {
    const int i = it + 16 * r;
    const float inv = 1.0f / lrow[i];
    float* xp = X + base + (size_t)(i0 + i) * 64 + 4 * jt;
    float4 xv = *(const float4*)xp;
    xv.x += O[r][0] * inv;
    xv.y += O[r][1] * inv;
    xv.z += O[r][2] * inv;
    xv.w += O[r][3] * inv;
    *(float4*)xp = xv;
  }
}

// ---------------------------------------------------------------------------
// 4) head: pred[b,k] = (mean_c X[b,:,c]) . last_W[k,:] + last_b[k]
// ---------------------------------------------------------------------------
__global__ __launch_bounds__(256) void k_head(
    const float* __restrict__ X, const float* __restrict__ lW,
    const float* __restrict__ lb, float* __restrict__ out) {
  __shared__ float meanv[DIMN];
  __shared__ float red[256];
  const int b    = blockIdx.x;
  const int tid  = threadIdx.x;
  const int lane = tid & 63;
  const int w    = tid >> 6;
  const float* Xb = X + (size_t)b * DIMN * 64;
  for (int n = w; n < DIMN; n += 4) {
    float v = Xb[(size_t)n * 64 + lane];
    #pragma unroll
    for (int off = 32; off > 0; off >>= 1)
      v += __shfl_down(v, off, 64);
    if (lane == 0) meanv[n] = v * (1.0f / 64.0f);
  }
  __syncthreads();
  float acc[NCLS];
  #pragma unroll
  for (int k = 0; k < NCLS; ++k) acc[k] = 0.f;
  for (int n = tid; n < DIMN; n += 256) {
    const float m = meanv[n];
    #pragma unroll
    for (int k = 0; k < NCLS; ++k)
      acc[k] = fmaf(m, lW[k * DIMN + n], acc[k]);
  }
  for (int k = 0; k < NCLS; ++k) {
    red[tid] = acc[k];
    __syncthreads();
    for (int s = 128; s > 0; s >>= 1) {
      if (tid < s) red[tid] += red[tid + s];
      __syncthreads();
    }
    if (tid == 0) out[b * NCLS + k] = red[0] + lb[k];
    __syncthreads();
  }
}

// ---------------------------------------------------------------------------
// launch: transpose -> 8x (qkv -> attn, X updated in place) -> head
// workspace: X (8 MB) + Q/K/V (8 MB each) = 32 MB
// ---------------------------------------------------------------------------
extern "C" void kernel_launch(void* const* d_in, const int* in_sizes, int n_in,
                              void* d_out, int out_size, void* d_ws, size_t ws_size,
                              hipStream_t stream) {
  const float* image = (const float*)d_in[0];
  const float* WV    = (const float*)d_in[1];
  const float* WK    = (const float*)d_in[2];
  const float* WQ    = (const float*)d_in[3];
  const float* lW    = (const float*)d_in[4];
  const float* lb    = (const float*)d_in[5];
  float* out = (float*)d_out;

  float* ws = (float*)d_ws;
  const size_t NELEM = (size_t)BB * DIMN * CCH;  // 2,097,152
  float* X = ws;
  float* Q = ws + NELEM;
  float* K = ws + 2 * NELEM;
  float* V = ws + 3 * NELEM;

  k_transpose<<<dim3(DIMN / 64, BB), 256, 0, stream>>>(image, X);
  for (int layer = 0; layer < 8; ++layer) {
    k_qkv<<<(BB * DIMN) / 16, 256, 0, stream>>>(X, WQ, WK, WV, Q, K, V);
    k_attn<<<dim3(DIMN / 64, BB), 256, 0, stream>>>(Q, K, V, X);
  }
  k_head<<<BB, 256, 0, stream>>>(X, lW, lb, out);
}

// Round 3
// 1157.695 us; speedup vs baseline: 1.9907x; 1.9907x over previous
//
#include <hip/hip_runtime.h>
#include <math.h>

#define BB    32
#define CCH   64
#define DIMN  1024
#define NCLS  10

typedef __attribute__((ext_vector_type(8))) short bf16x8;
typedef __attribute__((ext_vector_type(4))) float f32x4;
typedef __attribute__((ext_vector_type(4))) unsigned short us4;

#define MFMA16(a, b, c) __builtin_amdgcn_mfma_f32_16x16x32_bf16(a, b, c, 0, 0, 0)

__device__ __forceinline__ unsigned short f2bf(float x) {
  unsigned u = __float_as_uint(x);
  unsigned r = u + 0x7fffu + ((u >> 16) & 1u);   // round-to-nearest-even
  return (unsigned short)(r >> 16);
}
__device__ __forceinline__ float bf2f(unsigned short h) {
  return __uint_as_float(((unsigned)h) << 16);
}
// x == h + m + l to ~2^-26 relative (each residual is fp32-exact)
__device__ __forceinline__ void split3(float x, unsigned short& h,
                                       unsigned short& m, unsigned short& l) {
  h = f2bf(x); float hf = bf2f(h);
  float r = x - hf;
  m = f2bf(r); float mf = bf2f(m);
  l = f2bf(r - mf);
}
__device__ __forceinline__ bf16x8 ld8(const unsigned short* p) {
  union { bf16x8 v; us4 h[2]; } u;
  u.h[0] = *(const us4*)(p);
  u.h[1] = *(const us4*)(p + 4);
  return u.v;
}

// ---------------------------------------------------------------------------
// 1) transpose: image (B,C,DIM) -> X (B,DIM,C)
// ---------------------------------------------------------------------------
__global__ __launch_bounds__(256) void k_transpose(const float* __restrict__ img,
                                                   float* __restrict__ X) {
  __shared__ float tile[64][65];
  const int b  = blockIdx.y;
  const int n0 = blockIdx.x * 64;
  const int tx = threadIdx.x & 63;
  const int ty = threadIdx.x >> 6;
  const float* src = img + (size_t)b * CCH * DIMN;
  #pragma unroll
  for (int c = ty; c < 64; c += 4)
    tile[c][tx] = src[(size_t)c * DIMN + n0 + tx];
  __syncthreads();
  float* dst = X + (size_t)b * DIMN * CCH;
  #pragma unroll
  for (int nn = ty; nn < 64; nn += 4)
    dst[(size_t)(n0 + nn) * CCH + tx] = tile[tx][nn];
}

// ---------------------------------------------------------------------------
// 2) QKV projection (fp32 VALU, sequential-j fmaf: fp32-noise-level, proven r1)
// ---------------------------------------------------------------------------
__global__ __launch_bounds__(256) void k_qkv(
    const float* __restrict__ X,
    const float* __restrict__ WQ, const float* __restrict__ WK,
    const float* __restrict__ WV,
    float* __restrict__ Q, float* __restrict__ K, float* __restrict__ V) {
  __shared__ float xs[16][64];
  const int c  = threadIdx.x & 63;
  const int tg = threadIdx.x >> 6;
  const size_t t0 = (size_t)blockIdx.x * 16;
  #pragma unroll
  for (int r = tg; r < 16; r += 4)
    xs[r][c] = X[(t0 + r) * 64 + c];
  __syncthreads();
  float qa[4] = {0.f,0.f,0.f,0.f};
  float ka[4] = {0.f,0.f,0.f,0.f};
  float va[4] = {0.f,0.f,0.f,0.f};
  for (int j = 0; j < 64; ++j) {
    const float wq = WQ[j * 64 + c];
    const float wk = WK[j * 64 + c];
    const float wv = WV[j * 64 + c];
    #pragma unroll
    for (int r = 0; r < 4; ++r) {
      const float x = xs[tg * 4 + r][j];
      qa[r] = fmaf(x, wq, qa[r]);
      ka[r] = fmaf(x, wk, ka[r]);
      va[r] = fmaf(x, wv, va[r]);
    }
  }
  #pragma unroll
  for (int r = 0; r < 4; ++r) {
    const size_t idx = (t0 + tg * 4 + r) * 64 + c;
    Q[idx] = qa[r]; K[idx] = ka[r]; V[idx] = va[r];
  }
}

// ---------------------------------------------------------------------------
// 3) MFMA flash attention, full fp32-fidelity via compensated bf16 splits.
//    Scores: Q,K 3-term -> 6 products (~2^-26 rel).
//    PV:     P round-trips LDS as fp32, split 3-term on read; V 3-term in LDS;
//            6 products (~2^-26 rel). Layer-1 soft-softmax rows (the round-2
//            killer at P-bf16 2^-8) now carry only fp32-level noise.
//    32-key tiles: LDS = K 13.8 + V^T 15.4 + P 9.2 = 38.4 KB.
//    Wave w owns S rows 16w..16w+15: softmax + P wave-local, 2 barriers/iter.
//    All LDS strides 16B-aligned, hot patterns <=2-way bank-aliased (free).
// ---------------------------------------------------------------------------
__global__ __launch_bounds__(256) void k_attn_mfma(
    const float* __restrict__ Qg, const float* __restrict__ Kg,
    const float* __restrict__ Vg, float* __restrict__ X) {
  __shared__ __align__(16) unsigned short Kh[32 * 72];
  __shared__ __align__(16) unsigned short Km[32 * 72];
  __shared__ __align__(16) unsigned short Kl[32 * 72];
  __shared__ __align__(16) unsigned short Vh[64 * 40];   // V^T: [c][j]
  __shared__ __align__(16) unsigned short Vm[64 * 40];
  __shared__ __align__(16) unsigned short Vl[64 * 40];
  __shared__ __align__(16) float Pb[64 * 36];            // fp32 P round-trip

  const int tid  = threadIdx.x;
  const int w    = tid >> 6;       // wave 0..3 -> S rows 16w..16w+15
  const int lane = tid & 63;
  const int ln   = lane & 15;      // fragment row/col index
  const int q    = lane >> 4;      // k-chunk selector
  const int b    = blockIdx.y;
  const int i0   = blockIdx.x * 64;
  const size_t base = (size_t)b * (DIMN * 64);
  const float scale = 0.03125f;    // DIM^-0.5

  const float* Kbase = Kg + base;
  const float* Vbase = Vg + base;

  // ---- Q fragments in registers: 3-term split, 2 k-chunks ------------------
  bf16x8 qh[2], qm[2], ql[2];
  {
    const int mrow = i0 + 16 * w + ln;
    const float* qp = Qg + base + (size_t)mrow * 64 + 8 * q;
    #pragma unroll
    for (int s = 0; s < 2; ++s) {
      const float4 x0 = ((const float4*)(qp + 32 * s))[0];
      const float4 x1 = ((const float4*)(qp + 32 * s))[1];
      const float xv[8] = {x0.x, x0.y, x0.z, x0.w, x1.x, x1.y, x1.z, x1.w};
      union { bf16x8 v; unsigned short e[8]; } uh, um, ul;
      #pragma unroll
      for (int j = 0; j < 8; ++j) {
        unsigned short h, m, l;
        split3(xv[j], h, m, l);
        uh.e[j] = h; um.e[j] = m; ul.e[j] = l;
      }
      qh[s] = uh.v; qm[s] = um.v; ql[s] = ul.v;
    }
  }

  f32x4 O[4];
  #pragma unroll
  for (int ct = 0; ct < 4; ++ct) O[ct] = (f32x4){0.f, 0.f, 0.f, 0.f};
  float m_run[4] = {-INFINITY, -INFINITY, -INFINITY, -INFINITY};
  float l_run[4] = {0.f, 0.f, 0.f, 0.f};

  for (int kt = 0; kt < 32; ++kt) {
    __syncthreads();   // previous iteration's K/V readers done

    // ---- stage K tile (32 keys x 64 d), 3-term, row-major [j][d] -----------
    {
      const int j  = tid >> 3;     // 0..31
      const int dq = tid & 7;      // 8-float group
      const float* kp = Kbase + (size_t)(kt * 32 + j) * 64 + 8 * dq;
      const float4 a0 = ((const float4*)kp)[0];
      const float4 a1 = ((const float4*)kp)[1];
      const float xv[8] = {a0.x, a0.y, a0.z, a0.w, a1.x, a1.y, a1.z, a1.w};
      const int o = j * 72 + 8 * dq;
      us4 hh[2], mm[2], llv[2];
      #pragma unroll
      for (int e = 0; e < 8; ++e) {
        unsigned short h, m, l;
        split3(xv[e], h, m, l);
        hh[e >> 2][e & 3] = h; mm[e >> 2][e & 3] = m; llv[e >> 2][e & 3] = l;
      }
      *(us4*)&Kh[o] = hh[0];  *(us4*)&Kh[o + 4] = hh[1];
      *(us4*)&Km[o] = mm[0];  *(us4*)&Km[o + 4] = mm[1];
      *(us4*)&Kl[o] = llv[0]; *(us4*)&Kl[o + 4] = llv[1];
    }
    // ---- stage V tile transposed (64 c x 32 j), 3-term ---------------------
    {
      const int jp = tid >> 4;     // 0..15 -> keys 2jp, 2jp+1
      const int cq = tid & 15;     // c-group of 4
      const float* vp = Vbase + (size_t)(kt * 32 + 2 * jp) * 64 + 4 * cq;
      const float4 a = *(const float4*)vp;
      const float4 bb = *(const float4*)(vp + 64);
      const float av[4] = {a.x, a.y, a.z, a.w};
      const float bv[4] = {bb.x, bb.y, bb.z, bb.w};
      #pragma unroll
      for (int e = 0; e < 4; ++e) {
        const int c = 4 * cq + e;
        unsigned short h1, m1, l1, h2, m2, l2;
        split3(av[e], h1, m1, l1);
        split3(bv[e], h2, m2, l2);
        *(unsigned int*)&Vh[c * 40 + 2 * jp] = (unsigned)h1 | ((unsigned)h2 << 16);
        *(unsigned int*)&Vm[c * 40 + 2 * jp] = (unsigned)m1 | ((unsigned)m2 << 16);
        *(unsigned int*)&Vl[c * 40 + 2 * jp] = (unsigned)l1 | ((unsigned)l2 << 16);
      }
    }
    __syncthreads();

    // ---- S strip = Q . K^T via 6-product compensated MFMA ------------------
    f32x4 sacc[2];
    #pragma unroll
    for (int ct = 0; ct < 2; ++ct) {
      f32x4 a = (f32x4){0.f, 0.f, 0.f, 0.f};
      #pragma unroll
      for (int s = 0; s < 2; ++s) {
        const int ko = (16 * ct + ln) * 72 + 32 * s + 8 * q;
        const bf16x8 bh = ld8(&Kh[ko]);
        const bf16x8 bm = ld8(&Km[ko]);
        const bf16x8 bl = ld8(&Kl[ko]);
        a = MFMA16(ql[s], bh, a);   // smallest terms first
        a = MFMA16(qh[s], bl, a);
        a = MFMA16(qm[s], bm, a);
        a = MFMA16(qm[s], bh, a);
        a = MFMA16(qh[s], bm, a);
        a = MFMA16(qh[s], bh, a);
      }
      sacc[ct] = a;
    }

    // ---- wave-local online softmax (lane rows 4q+r) ------------------------
    float rmax[4];
    #pragma unroll
    for (int r = 0; r < 4; ++r)
      rmax[r] = fmaxf(sacc[0][r], sacc[1][r]);
    #pragma unroll
    for (int mk = 1; mk <= 8; mk <<= 1) {
      #pragma unroll
      for (int r = 0; r < 4; ++r)
        rmax[r] = fmaxf(rmax[r], __shfl_xor(rmax[r], mk, 64));
    }
    float alpha[4], rsum[4];
    #pragma unroll
    for (int r = 0; r < 4; ++r) {
      const float mnew = fmaxf(m_run[r], rmax[r] * scale);
      alpha[r] = __expf(m_run[r] - mnew);   // exact 0/1 in one-hot regime
      m_run[r] = mnew;
      rsum[r] = 0.f;
    }
    #pragma unroll
    for (int ct = 0; ct < 2; ++ct) {
      #pragma unroll
      for (int r = 0; r < 4; ++r) {
        const float pv = __expf(sacc[ct][r] * scale - m_run[r]);
        rsum[r] += pv;
        Pb[(16 * w + 4 * q + r) * 36 + ln + 16 * ct] = pv;   // fp32!
      }
    }
    #pragma unroll
    for (int mk = 1; mk <= 8; mk <<= 1) {
      #pragma unroll
      for (int r = 0; r < 4; ++r)
        rsum[r] += __shfl_xor(rsum[r], mk, 64);
    }
    #pragma unroll
    for (int r = 0; r < 4; ++r)
      l_run[r] = l_run[r] * alpha[r] + rsum[r];

    // ---- O rescale ---------------------------------------------------------
    #pragma unroll
    for (int ct = 0; ct < 4; ++ct) {
      #pragma unroll
      for (int r = 0; r < 4; ++r) O[ct][r] *= alpha[r];
    }

    // ---- P A-fragment: read own rows as fp32, split 3-term -----------------
    bf16x8 ph, pm, pl;
    {
      const float* pp = &Pb[(16 * w + ln) * 36 + 8 * q];   // wave-local rows
      const float4 p0 = ((const float4*)pp)[0];
      const float4 p1 = ((const float4*)pp)[1];
      const float pvv[8] = {p0.x, p0.y, p0.z, p0.w, p1.x, p1.y, p1.z, p1.w};
      union { bf16x8 v; unsigned short e[8]; } uh, um, ul;
      #pragma unroll
      for (int j = 0; j < 8; ++j) {
        unsigned short h, m, l;
        split3(pvv[j], h, m, l);
        uh.e[j] = h; um.e[j] = m; ul.e[j] = l;
      }
      ph = uh.v; pm = um.v; pl = ul.v;
    }

    // ---- O += P @ V, 6-product compensated ---------------------------------
    #pragma unroll
    for (int ct = 0; ct < 4; ++ct) {
      const int vo = (16 * ct + ln) * 40 + 8 * q;
      const bf16x8 vvh = ld8(&Vh[vo]);
      const bf16x8 vvm = ld8(&Vm[vo]);
      const bf16x8 vvl = ld8(&Vl[vo]);
      O[ct] = MFMA16(ph, vvh, O[ct]);
      O[ct] = MFMA16(ph, vvm, O[ct]);
      O[ct] = MFMA16(pm, vvh, O[ct]);
      O[ct] = MFMA16(pm, vvm, O[ct]);
      O[ct] = MFMA16(ph, vvl, O[ct]);
      O[ct] = MFMA16(pl, vvh, O[ct]);
    }
  }

  // ---- epilogue: X += O / l (block owns its 64 rows exclusively) -----------
  float linv[4];
  #pragma unroll
  for (int r = 0; r < 4; ++r) linv[r] = 1.0f / l_run[r];
  #pragma unroll
  for (int ct = 0; ct < 4; ++ct) {
    #pragma unroll
    for (int r = 0; r < 4; ++r) {
      float* xp = X + base + (size_t)(i0 + 16 * w + 4 * q + r) * 64 + ln + 16 * ct;
      *xp += O[ct][r] * linv[r];
    }
  }
}

// ---------------------------------------------------------------------------
// 4) head: pred[b,k] = (mean_c X[b,:,c]) . last_W[k,:] + last_b[k]
// ---------------------------------------------------------------------------
__global__ __launch_bounds__(256) void k_head(
    const float* __restrict__ X, const float* __restrict__ lW,
    const float* __restrict__ lb, float* __restrict__ out) {
  __shared__ float meanv[DIMN];
  __shared__ float red[256];
  const int b    = blockIdx.x;
  const int tid  = threadIdx.x;
  const int lane = tid & 63;
  const int w    = tid >> 6;
  const float* Xb = X + (size_t)b * DIMN * 64;
  for (int n = w; n < DIMN; n += 4) {
    float v = Xb[(size_t)n * 64 + lane];
    #pragma unroll
    for (int off = 32; off > 0; off >>= 1)
      v += __shfl_down(v, off, 64);
    if (lane == 0) meanv[n] = v * (1.0f / 64.0f);
  }
  __syncthreads();
  float acc[NCLS];
  #pragma unroll
  for (int k = 0; k < NCLS; ++k) acc[k] = 0.f;
  for (int n = tid; n < DIMN; n += 256) {
    const float m = meanv[n];
    #pragma unroll
    for (int k = 0; k < NCLS; ++k)
      acc[k] = fmaf(m, lW[k * DIMN + n], acc[k]);
  }
  for (int k = 0; k < NCLS; ++k) {
    red[tid] = acc[k];
    __syncthreads();
    for (int s = 128; s > 0; s >>= 1) {
      if (tid < s) red[tid] += red[tid + s];
      __syncthreads();
    }
    if (tid == 0) out[b * NCLS + k] = red[0] + lb[k];
    __syncthreads();
  }
}

// ---------------------------------------------------------------------------
// launch
// ---------------------------------------------------------------------------
extern "C" void kernel_launch(void* const* d_in, const int* in_sizes, int n_in,
                              void* d_out, int out_size, void* d_ws, size_t ws_size,
                              hipStream_t stream) {
  const float* image = (const float*)d_in[0];
  const float* WV    = (const float*)d_in[1];
  const float* WK    = (const float*)d_in[2];
  const float* WQ    = (const float*)d_in[3];
  const float* lW    = (const float*)d_in[4];
  const float* lb    = (const float*)d_in[5];
  float* out = (float*)d_out;

  float* ws = (float*)d_ws;
  const size_t NELEM = (size_t)BB * DIMN * CCH;
  float* X = ws;
  float* Q = ws + NELEM;
  float* K = ws + 2 * NELEM;
  float* V = ws + 3 * NELEM;

  k_transpose<<<dim3(DIMN / 64, BB), 256, 0, stream>>>(image, X);
  for (int layer = 0; layer < 8; ++layer) {
    k_qkv<<<(BB * DIMN) / 16, 256, 0, stream>>>(X, WQ, WK, WV, Q, K, V);
    k_attn_mfma<<<dim3(DIMN / 64, BB), 256, 0, stream>>>(Q, K, V, X);
  }
  k_head<<<BB, 256, 0, stream>>>(X, lW, lb, out);
}